// Round 10
// baseline (155.726 us; speedup 1.0000x reference)
//
#include <hip/hip_runtime.h>

// DepthwiseTemporalConv: I[n,c,t] = x_flat[n*16384 + c*64 + t]
// Y[n,c,t] = sum_{k=0}^{63-t} I[n,c,t+k] * W[c,k]
// out_flat[(n>>10)*16777216 + c*65536 + t*1024 + (n&1023)] = Y[n,c,t]
//
// R10 = R9 kernel unchanged; ONLY the grid->(n_tile,c) map changes.
// Theory: the ~100us floor across R1-R9 is write-channel hotspotting.
// Store channel = (16t + p>>6) mod 128 is c-INDEPENDENT; R9's map (c=bid&255)
// made the ~2048 concurrent blocks span all c but only ~8 n_tiles, so waves in
// loose t-lockstep concentrated stores on ~16 of 128 channels. Bit-interleaved
// bijection below spreads n_tile (write channels) within every ~512-bid window
// while keeping c varying (read channels).
//
// Kernel (from R9): no LDS/barriers; 16 opaque inline-asm global_load_dwordx4
// per thread (un-rematerializable -> row stays in regs/AGPRs; R2/R3 remat and
// R4 spill defeated), one vmcnt(0)+sched_barrier(0), t-outer 2-chain
// triangular compute, coalesced 256B stores.

constexpr int Cc = 256;
constexpr int Tt = 64;
constexpr int Kk = 64;
constexpr int CT = Cc * Tt;   // 16384

typedef float f32x4 __attribute__((ext_vector_type(4)));

__global__ __launch_bounds__(128, 5)
void DepthwiseTemporalConv_24962349924982_kernel(const float* __restrict__ x,
                                                 const float* __restrict__ w,
                                                 float* __restrict__ out) {
    const int tid = threadIdx.x;
    const int bid = blockIdx.x;
    // bijective remap of 13 grid bits: c <- {b3..b0 (hi nibble), b12..b9 (lo)},
    // n_tile <- b8..b4. Consecutive bids vary c's hi-nibble AND (every 16)
    // n_tile -> both read and write channels spread in any concurrency window.
    const int c      = ((bid & 15) << 4) | ((bid >> 9) & 15);
    const int n_tile = (bid >> 4) & 31;
    const int n  = n_tile * 128 + tid;
    const int cu = __builtin_amdgcn_readfirstlane(c);

    // ---- issue 16 opaque loads for this thread's contiguous 256B row.
    const float* rowp = x + (size_t)n * CT + (size_t)cu * Tt;
    f32x4 q[16];
    #pragma unroll
    for (int m = 0; m < 16; ++m) {
        asm volatile("global_load_dwordx4 %0, %1, off offset:%2"
                     : "=v"(q[m])
                     : "v"(rowp), "i"(16 * m));
    }

    // ---- weights: block-uniform -> scalar s_loads into SGPRs
    float wr[Kk];
    {
        const float4* wp = (const float4*)(w + (size_t)cu * Kk);
        #pragma unroll
        for (int m = 0; m < 16; ++m) {
            const float4 v = wp[m];
            wr[4*m+0] = v.x; wr[4*m+1] = v.y; wr[4*m+2] = v.z; wr[4*m+3] = v.w;
        }
    }

    // ---- drain the 16 loads; fence scheduler so no consumer hoists above
    asm volatile("s_waitcnt vmcnt(0)" ::: "memory");
    __builtin_amdgcn_sched_barrier(0);

    // register-rename q -> xr
    float xr[Tt];
    #pragma unroll
    for (int m = 0; m < 16; ++m) {
        xr[4*m+0] = q[m][0]; xr[4*m+1] = q[m][1];
        xr[4*m+2] = q[m][2]; xr[4*m+3] = q[m][3];
    }

    // ---- triangular suffix correlation, 2 accumulator chains; stores
    // 256B-contiguous per wave per t.
    float* __restrict__ obase = out + (size_t)(n >> 10) * (Cc * Tt * 1024)
                                    + (size_t)cu * (Tt * 1024) + (n & 1023);
    #pragma unroll
    for (int t = 0; t < Tt; ++t) {
        const int len = Tt - t;
        float a0 = 0.f, a1 = 0.f;
        #pragma unroll
        for (int k = 0; k + 1 < len; k += 2) {
            a0 = fmaf(xr[t + k],     wr[k],     a0);
            a1 = fmaf(xr[t + k + 1], wr[k + 1], a1);
        }
        if (len & 1) a0 = fmaf(xr[Tt - 1], wr[len - 1], a0);
        obase[(size_t)t * 1024] = a0 + a1;
    }
}

extern "C" void kernel_launch(void* const* d_in, const int* in_sizes, int n_in,
                              void* d_out, int out_size, void* d_ws, size_t ws_size,
                              hipStream_t stream) {
    const float* x = (const float*)d_in[0];
    const float* w = (const float*)d_in[1];
    float* out = (float*)d_out;
    // 32 n-tiles x 256 c = 8192 two-wave blocks (bit-interleaved mapping)
    DepthwiseTemporalConv_24962349924982_kernel<<<dim3(8192), dim3(128), 0, stream>>>(x, w, out);
}

// Round 11
// 143.439 us; speedup vs baseline: 1.0857x; 1.0857x over previous
//
#include <hip/hip_runtime.h>

// DepthwiseTemporalConv: I[n,c,t] = x_flat[n*16384 + c*64 + t]
// Y[n,c,t] = sum_{k=0}^{63-t} I[n,c,t+k] * W[c,k]
// out_flat[(n>>10)*16777216 + c*65536 + t*1024 + (n&1023)] = Y[n,c,t]
//
// R11 = R9 thread-body unchanged; ONLY the decomposition changes.
// Theory: the ~150us plateau is WRITE temporal fragmentation — each output
// 4-KB page (fixed d,c,t) was assembled from 8-16 blocks scattered across the
// grid timeline, so L2 evicted isolated 256-B dirty granules (DRAM row
// thrash). Now a block owns 512 consecutive p of one (d,c) and its h-sibling
// (adjacent bid, concurrent) owns the rest: each (d,c) 256-KB output slab is
// written densely and temporally together -> full-page evictions -> dense
// DRAM write streams. Reads unchanged per-thread (256-B row gather, proven
// ~fine: FETCH 134MB); whole grid is ~co-resident, c varies fastest -> dense
// collective x sweep.

constexpr int Cc = 256;
constexpr int Tt = 64;
constexpr int Kk = 64;
constexpr int CT = Cc * Tt;   // 16384

typedef float f32x4 __attribute__((ext_vector_type(4)));

__global__ __launch_bounds__(512, 4)
void DepthwiseTemporalConv_24962349924982_kernel(const float* __restrict__ x,
                                                 const float* __restrict__ w,
                                                 float* __restrict__ out) {
    const int tid = threadIdx.x;      // 0..511
    const int bid = blockIdx.x;       // 2048 blocks
    const int h = bid & 1;            // page half (sibling bids adjacent)
    const int c = (bid >> 1) & 255;   // channel (fast -> read spread)
    const int d = bid >> 9;           // batch (slow)
    const int n  = d * 1024 + h * 512 + tid;   // 512 consecutive n per block
    const int cu = __builtin_amdgcn_readfirstlane(c);

    // ---- issue 16 opaque loads for this thread's contiguous 256B row.
    const float* rowp = x + (size_t)n * CT + (size_t)cu * Tt;
    f32x4 q[16];
    #pragma unroll
    for (int m = 0; m < 16; ++m) {
        asm volatile("global_load_dwordx4 %0, %1, off offset:%2"
                     : "=v"(q[m])
                     : "v"(rowp), "i"(16 * m));
    }

    // ---- weights: block-uniform -> scalar s_loads into SGPRs
    float wr[Kk];
    {
        const float4* wp = (const float4*)(w + (size_t)cu * Kk);
        #pragma unroll
        for (int m = 0; m < 16; ++m) {
            const float4 v = wp[m];
            wr[4*m+0] = v.x; wr[4*m+1] = v.y; wr[4*m+2] = v.z; wr[4*m+3] = v.w;
        }
    }

    // ---- drain the 16 loads; fence scheduler so no consumer hoists above
    asm volatile("s_waitcnt vmcnt(0)" ::: "memory");
    __builtin_amdgcn_sched_barrier(0);

    // register-rename q -> xr
    float xr[Tt];
    #pragma unroll
    for (int m = 0; m < 16; ++m) {
        xr[4*m+0] = q[m][0]; xr[4*m+1] = q[m][1];
        xr[4*m+2] = q[m][2]; xr[4*m+3] = q[m][3];
    }

    // ---- triangular suffix correlation, 2 accumulator chains; stores
    // 256B-contiguous per wave per t; block+sibling cover the full 4-KB page.
    float* __restrict__ obase = out + (size_t)(n >> 10) * (Cc * Tt * 1024)
                                    + (size_t)cu * (Tt * 1024) + (n & 1023);
    #pragma unroll
    for (int t = 0; t < Tt; ++t) {
        const int len = Tt - t;
        float a0 = 0.f, a1 = 0.f;
        #pragma unroll
        for (int k = 0; k + 1 < len; k += 2) {
            a0 = fmaf(xr[t + k],     wr[k],     a0);
            a1 = fmaf(xr[t + k + 1], wr[k + 1], a1);
        }
        if (len & 1) a0 = fmaf(xr[Tt - 1], wr[len - 1], a0);
        obase[(size_t)t * 1024] = a0 + a1;
    }
}

extern "C" void kernel_launch(void* const* d_in, const int* in_sizes, int n_in,
                              void* d_out, int out_size, void* d_ws, size_t ws_size,
                              hipStream_t stream) {
    const float* x = (const float*)d_in[0];
    const float* w = (const float*)d_in[1];
    float* out = (float*)d_out;
    // 4 d x 256 c x 2 halves = 2048 blocks of 512 threads
    DepthwiseTemporalConv_24962349924982_kernel<<<dim3(2048), dim3(512), 0, stream>>>(x, w, out);
}